// Round 14
// baseline (517.853 us; speedup 1.0000x reference)
//
#include <hip/hip_runtime.h>
#include <hip/hip_bf16.h>

#define BB  64
#define JJ  2048
#define DI  16
#define KC  32
#define DOO 32
#define NKO 1024   // KC*DOO

typedef __bf16 bf16;
typedef __attribute__((ext_vector_type(8)))  __bf16 bf16x8;
typedef __attribute__((ext_vector_type(4)))  __bf16 bf16x4;
typedef __attribute__((ext_vector_type(4)))  float  f32x4;
typedef __attribute__((ext_vector_type(16))) float  f32x16;

// ======== 32x32x16 MFMA scheme ========
// D = A(32x16) * B(16x32).  A = W-slice (rows = o), B = X (cols = b). K = i (16).
// A-frag: lane l holds row o = l&31, k i = (l>>5)*8 + e
// B-frag: lane l holds col b = l&31, k i = (l>>5)*8 + e
// C/D   : col b = lane&31, row o = (reg&3) + 8*(reg>>2) + 4*(lane>>5)   [m74/m101]

// ---------------- prep: X f32 [B][J][Di] -> B-fragment layout ----------------
__global__ __launch_bounds__(256)
void prep_x3(const float* __restrict__ X, bf16* __restrict__ Xfrag)
{
    int flat = blockIdx.x * 256 + threadIdx.x;    // < 262144
    int lane = flat & 63;
    int c01  = (flat >> 6) & 1;
    int j    = flat >> 7;
    int b    = c01 * 32 + (lane & 31);
    int i0   = (lane >> 5) * 8;
    const float* src = X + ((size_t)b * JJ + j) * DI + i0;
    bf16x8 o8;
#pragma unroll
    for (int e = 0; e < 8; ++e) o8[e] = (bf16)src[e];
    *reinterpret_cast<bf16x8*>(Xfrag + (size_t)flat * 8) = o8;
}

// XCD-aware decodes (bijective for the grids used).
__device__ __forceinline__ void decode_qjr(int id, int& q, int& jr)   // grid 4P, P%8==0
{
    q = (id >> 3) & 3; jr = ((id >> 5) << 3) | (id & 7);
}
__device__ __forceinline__ void decode_q8(int id, int& q8, int& jr)   // grid 8P, P%8==0
{
    q8 = (id >> 3) & 7; jr = ((id >> 6) << 3) | (id & 7);
}
__device__ __forceinline__ int decode_jg(int id)    // grid 1024
{
    return (id & 7) * 128 + (id >> 3);
}
__device__ __forceinline__ void decode_f2(int id, int& c01, int& jr)  // grid 2P, P%8==0
{
    int xcd = id & 7; int m = id >> 3;
    c01 = m & 1; jr = ((m >> 1) << 3) | xcd;   // c01 pair of one jr shares an XCD
}

// ---------------- fused prep+init, 2-j batched ----------------
__global__ __launch_bounds__(512, 6)
void caps_init8(const bf16* __restrict__ Xfrag, const float* __restrict__ Wg,
                bf16* __restrict__ Wfrag, bf16* __restrict__ partial, int Jc)
{
    const int tid  = threadIdx.x;
    const int w    = tid >> 6;
    const int lane = tid & 63;
    const int o31  = lane & 31;
    const int hi   = lane >> 5;
    int q8, jr; decode_q8(blockIdx.x, q8, jr);
    const int unit = q8 * 8 + w;
    const int k    = unit & 31;
    const int c01  = unit >> 5;

    f32x16 acc = {};

    const int j0 = jr * Jc;
    int jend = j0 + Jc; if (jend > JJ) jend = JJ;

    int j = j0;
    for (; j + 1 < jend; j += 2) {
        const float* ws0 = Wg + (size_t)j * 16384 + (size_t)k * 512 + hi * 256 + o31;
        const float* ws1 = ws0 + 16384;
        float a0[8], a1[8];
#pragma unroll
        for (int e = 0; e < 8; ++e) a0[e] = ws0[e * 32];
#pragma unroll
        for (int e = 0; e < 8; ++e) a1[e] = ws1[e * 32];
        bf16x8 fw0, fw1;
#pragma unroll
        for (int e = 0; e < 8; ++e) { fw0[e] = (bf16)a0[e]; fw1[e] = (bf16)a1[e]; }
        if (c01 == 0) {
            *reinterpret_cast<bf16x8*>(Wfrag + (((size_t)j * 32 + k) * 64 + lane) * 8)       = fw0;
            *reinterpret_cast<bf16x8*>(Wfrag + (((size_t)(j + 1) * 32 + k) * 64 + lane) * 8) = fw1;
        }
        bf16x8 fx0 = *reinterpret_cast<const bf16x8*>(Xfrag + (((size_t)j * 2 + c01) * 64 + lane) * 8);
        bf16x8 fx1 = *reinterpret_cast<const bf16x8*>(Xfrag + (((size_t)(j + 1) * 2 + c01) * 64 + lane) * 8);
        acc = __builtin_amdgcn_mfma_f32_32x32x16_bf16(fw0, fx0, acc, 0, 0, 0);
        acc = __builtin_amdgcn_mfma_f32_32x32x16_bf16(fw1, fx1, acc, 0, 0, 0);
    }
    for (; j < jend; ++j) {
        const float* ws = Wg + (size_t)j * 16384 + (size_t)k * 512 + hi * 256 + o31;
        bf16x8 fw;
#pragma unroll
        for (int e = 0; e < 8; ++e) fw[e] = (bf16)ws[e * 32];
        if (c01 == 0)
            *reinterpret_cast<bf16x8*>(Wfrag + (((size_t)j * 32 + k) * 64 + lane) * 8) = fw;
        bf16x8 fx = *reinterpret_cast<const bf16x8*>(Xfrag + (((size_t)j * 2 + c01) * 64 + lane) * 8);
        acc = __builtin_amdgcn_mfma_f32_32x32x16_bf16(fw, fx, acc, 0, 0, 0);
    }

    bf16* pout = partial + (size_t)jr * (BB * NKO);
#pragma unroll
    for (int qq = 0; qq < 4; ++qq) {
        bf16x4 o4;
#pragma unroll
        for (int rr = 0; rr < 4; ++rr) o4[rr] = (bf16)(acc[qq * 4 + rr] * 0.03125f);
        *reinterpret_cast<bf16x4*>(pout + (((size_t)unit * 4 + qq) * 64 + lane) * 4) = o4;
    }
}

// ---------------- fused routing iteration: logits + softmax + accumulate ----------------
// Block 1024 = 16 waves, owns (c01, jr); wave w owns k in {2w, 2w+1}. Grid 2P, P%8==0.
// Per j: phase A: 2 MFMA -> logit dots (coalesced vsumT) -> shfl(32) -> lex[pb];
//        ONE barrier (lex double-buffered);
//        phase B/C: per-b31 softmax via LDS broadcast reads; hat RECOMPUTED from
//        still-live fw/fx (nothing bulky crosses the barrier); acc[2][16].
__global__ __launch_bounds__(1024, 8)
void caps_fused(const bf16* __restrict__ Xfrag, const bf16* __restrict__ Wfrag,
                const float* __restrict__ vsumT, bf16* __restrict__ partial, int Jc)
{
    __shared__ float lex[2][32][32];    // [buf][k][b31] = 8 KB

    const int tid  = threadIdx.x;
    const int w    = tid >> 6;          // 0..15
    const int lane = tid & 63;
    const int b31  = lane & 31;
    const int hi   = lane >> 5;
    int c01, jr; decode_f2(blockIdx.x, c01, jr);
    const int k0   = 2 * w;
    const int k1   = 2 * w + 1;
    const int b    = c01 * 32 + b31;

    const f32x16 ZV16 = {};
    f32x16 acc0 = ZV16, acc1 = ZV16;

    const int j0 = jr * Jc;
    int jend = j0 + Jc; if (jend > JJ) jend = JJ;

    const float* vt0 = vsumT + (size_t)k0 * 2048 + hi * 256 + b;   // + qq*512 + rr*64
    const float* vt1 = vsumT + (size_t)k1 * 2048 + hi * 256 + b;

    for (int j = j0; j < jend; ++j) {
        const int pb = j & 1;

        // ---- phase A: hat + logit dots (h transient; fw/fx stay live) ----
        bf16x8 fx = *reinterpret_cast<const bf16x8*>(Xfrag + (((size_t)j * 2 + c01) * 64 + lane) * 8);
        const bf16* wfp = Wfrag + (((size_t)j * 32 + k0) * 64 + lane) * 8;
        bf16x8 fw0 = *reinterpret_cast<const bf16x8*>(wfp);
        bf16x8 fw1 = *reinterpret_cast<const bf16x8*>(wfp + 512);

        float a0, a1;
        {
            f32x16 h = __builtin_amdgcn_mfma_f32_32x32x16_bf16(fw0, fx, ZV16, 0, 0, 0);
            a0 = 0.f;
#pragma unroll
            for (int qq = 0; qq < 4; ++qq)
#pragma unroll
                for (int rr = 0; rr < 4; ++rr)
                    a0 += h[qq * 4 + rr] * vt0[qq * 512 + rr * 64];
        }
        {
            f32x16 h = __builtin_amdgcn_mfma_f32_32x32x16_bf16(fw1, fx, ZV16, 0, 0, 0);
            a1 = 0.f;
#pragma unroll
            for (int qq = 0; qq < 4; ++qq)
#pragma unroll
                for (int rr = 0; rr < 4; ++rr)
                    a1 += h[qq * 4 + rr] * vt1[qq * 512 + rr * 64];
        }
        a0 += __shfl_xor(a0, 32, 64);
        a1 += __shfl_xor(a1, 32, 64);
        if (hi == 0) {
            lex[pb][k0][b31] = a0;
            lex[pb][k1][b31] = a1;
        }
        __syncthreads();   // single barrier per j (lex double-buffered)

        // ---- phase B: per-b31 softmax stats via LDS broadcast reads ----
        float mx = lex[pb][0][b31];
#pragma unroll
        for (int k = 1; k < 32; ++k) mx = fmaxf(mx, lex[pb][k][b31]);
        float sm = 0.f;
#pragma unroll
        for (int k = 0; k < 32; ++k) sm += __expf(lex[pb][k][b31] - mx);
        float inv = 1.0f / sm;
        float cw0 = __expf(a0 - mx) * inv;
        float cw1 = __expf(a1 - mx) * inv;

        // ---- phase C: recompute hat, weighted accumulate ----
        {
            f32x16 h = __builtin_amdgcn_mfma_f32_32x32x16_bf16(fw0, fx, ZV16, 0, 0, 0);
#pragma unroll
            for (int r = 0; r < 16; ++r) acc0[r] += cw0 * h[r];
        }
        {
            f32x16 h = __builtin_amdgcn_mfma_f32_32x32x16_bf16(fw1, fx, ZV16, 0, 0, 0);
#pragma unroll
            for (int r = 0; r < 16; ++r) acc1[r] += cw1 * h[r];
        }
    }

    bf16* pout = partial + (size_t)jr * (BB * NKO);
    const int u0 = c01 * 32 + k0;
#pragma unroll
    for (int qq = 0; qq < 4; ++qq) {
        bf16x4 o4;
#pragma unroll
        for (int rr = 0; rr < 4; ++rr) o4[rr] = (bf16)acc0[qq * 4 + rr];
        *reinterpret_cast<bf16x4*>(pout + (((size_t)u0 * 4 + qq) * 64 + lane) * 4) = o4;
    }
#pragma unroll
    for (int qq = 0; qq < 4; ++qq) {
        bf16x4 o4;
#pragma unroll
        for (int rr = 0; rr < 4; ++rr) o4[rr] = (bf16)acc1[qq * 4 + rr];
        *reinterpret_cast<bf16x4*>(pout + (((size_t)(u0 + 1) * 4 + qq) * 64 + lane) * 4) = o4;
    }
}

// ---------------- merged reduce: sum P slices + squash + update vsum/vsumT/out ----------------
__global__ __launch_bounds__(256)
void caps_red(const bf16* __restrict__ partial, float* __restrict__ vsum, float* __restrict__ vsumT,
              float* __restrict__ out, int P, int vmode, int wout)
{
    __shared__ float lds[4][32];
    const int unit = blockIdx.x;          // 0..63
    const int tid  = threadIdx.x;
    const int b31  = tid & 31;
    const int hi   = (tid >> 5) & 1;
    const int qq   = tid >> 6;
    const int k    = unit & 31;
    const int c01  = unit >> 5;

    const bf16* base = partial + (size_t)unit * 1024 + (size_t)tid * 4;
    f32x4 a = {};
    int p = 0;
    for (; p + 8 <= P; p += 8) {
        bf16x4 v[8];
#pragma unroll
        for (int u = 0; u < 8; ++u)
            v[u] = *reinterpret_cast<const bf16x4*>(base + (size_t)(p + u) * 65536);
#pragma unroll
        for (int u = 0; u < 8; ++u)
#pragma unroll
            for (int rr = 0; rr < 4; ++rr) a[rr] += (float)v[u][rr];
    }
    for (; p < P; ++p) {
        bf16x4 v = *reinterpret_cast<const bf16x4*>(base + (size_t)p * 65536);
#pragma unroll
        for (int rr = 0; rr < 4; ++rr) a[rr] += (float)v[rr];
    }

    float s2l = a[0] * a[0] + a[1] * a[1] + a[2] * a[2] + a[3] * a[3];
    s2l += __shfl_xor(s2l, 32, 64);
    if ((tid & 63) < 32) lds[qq][b31] = s2l;
    __syncthreads();
    float s2 = lds[0][b31] + lds[1][b31] + lds[2][b31] + lds[3][b31];
    float scale = s2 / (1.0f + s2) / sqrtf(s2 + 1e-7f);

    const int b  = c01 * 32 + b31;
    const int o0 = qq * 8 + hi * 4;
    size_t e0 = ((size_t)b * KC + k) * DOO + o0;
    float4 wv, nv;
    wv.x = scale * a[0]; wv.y = scale * a[1]; wv.z = scale * a[2]; wv.w = scale * a[3];
    if (vmode == 0) {
        nv = wv;
    } else if (vmode == 1) {
        float4 ov = *reinterpret_cast<const float4*>(vsum + e0);
        nv.x = ov.x + wv.x; nv.y = ov.y + wv.y; nv.z = ov.z + wv.z; nv.w = ov.w + wv.w;
    }
    if (vmode < 2) {
        *reinterpret_cast<float4*>(vsum + e0) = nv;
        vsumT[((size_t)k * 32 + o0 + 0) * 64 + b] = nv.x;
        vsumT[((size_t)k * 32 + o0 + 1) * 64 + b] = nv.y;
        vsumT[((size_t)k * 32 + o0 + 2) * 64 + b] = nv.z;
        vsumT[((size_t)k * 32 + o0 + 3) * 64 + b] = nv.w;
    }
    if (wout) *reinterpret_cast<float4*>(out + e0) = wv;
}

// ---------------- fallback kernels (raw f32 path) ----------------
template<int UF, int MODE>
__global__ __launch_bounds__(1024, 8)
void caps_mm32(const bf16* __restrict__ Xfrag, const bf16* __restrict__ Wfrag,
               const float* __restrict__ Xf, const float* __restrict__ Wf,
               const float* __restrict__ cbuf, bf16* __restrict__ partial, int Jc)
{
    const int tid  = threadIdx.x;
    const int w    = tid >> 6;
    const int lane = tid & 63;
    const int o31  = lane & 31;
    const int hi   = lane >> 5;
    int q, jr; decode_qjr(blockIdx.x, q, jr);
    const int unit = q * 16 + w;
    const int k    = unit & 31;
    const int c01  = unit >> 5;
    const int b    = c01 * 32 + o31;

    const f32x16 ZV16 = {};
    f32x16 acc = ZV16;

    const int j0 = jr * Jc;
    int jend = j0 + Jc; if (jend > JJ) jend = JJ;

    for (int j = j0; j < jend; ++j) {
        bf16x8 fx, fw;
        if constexpr (UF) {
            fx = *reinterpret_cast<const bf16x8*>(Xfrag + (((size_t)j * 2 + c01) * 64 + lane) * 8);
            fw = *reinterpret_cast<const bf16x8*>(Wfrag + (((size_t)j * 32 + k) * 64 + lane) * 8);
        } else {
            const float* xs = Xf + ((size_t)b * JJ + j) * DI + hi * 8;
#pragma unroll
            for (int e = 0; e < 8; ++e) fx[e] = (bf16)xs[e];
            const float* ws = Wf + (size_t)j * 16384 + (size_t)k * 512 + hi * 256 + o31;
#pragma unroll
            for (int e = 0; e < 8; ++e) fw[e] = (bf16)ws[e * 32];
        }
        if constexpr (MODE == 0) {
            acc = __builtin_amdgcn_mfma_f32_32x32x16_bf16(fw, fx, acc, 0, 0, 0);
        } else {
            float cw = cbuf[((size_t)j * 32 + k) * 64 + b];
            f32x16 h = __builtin_amdgcn_mfma_f32_32x32x16_bf16(fw, fx, ZV16, 0, 0, 0);
#pragma unroll
            for (int r = 0; r < 16; ++r) acc[r] += cw * h[r];
        }
    }

    const float esc = (MODE == 0) ? 0.03125f : 1.0f;
    bf16* pout = partial + (size_t)jr * (BB * NKO);
#pragma unroll
    for (int qq = 0; qq < 4; ++qq) {
        bf16x4 o4;
#pragma unroll
        for (int rr = 0; rr < 4; ++rr) o4[rr] = (bf16)(acc[qq * 4 + rr] * esc);
        *reinterpret_cast<bf16x4*>(pout + (((size_t)unit * 4 + qq) * 64 + lane) * 4) = o4;
    }
}

template<int UF>
__global__ __launch_bounds__(256, 6)
void caps_logits32(const bf16* __restrict__ Xfrag, const bf16* __restrict__ Wfrag,
                   const float* __restrict__ Xf, const float* __restrict__ Wf,
                   const float* __restrict__ vsum, float* __restrict__ cbuf)
{
    __shared__ float cl[2][64][33];

    const int tid  = threadIdx.x;
    const int w    = tid >> 6;
    const int lane = tid & 63;
    const int o31  = lane & 31;
    const int hi   = lane >> 5;
    const int jg   = decode_jg(blockIdx.x);
    const int j0   = jg * 2;
    const int jj   = w >> 1;
    const int c01  = w & 1;
    const int j    = j0 + jj;
    const int b    = c01 * 32 + o31;

    const f32x16 ZV16 = {};

    bf16x8 fx;
    if constexpr (UF) {
        fx = *reinterpret_cast<const bf16x8*>(Xfrag + (((size_t)j * 2 + c01) * 64 + lane) * 8);
    } else {
        const float* xs = Xf + ((size_t)b * JJ + j) * DI + hi * 8;
#pragma unroll
        for (int e = 0; e < 8; ++e) fx[e] = (bf16)xs[e];
    }

    const float* vb = vsum + (size_t)b * NKO + hi * 4;
    float lk[32];
#pragma unroll
    for (int k = 0; k < 32; ++k) {
        bf16x8 fw;
        if constexpr (UF) {
            fw = *reinterpret_cast<const bf16x8*>(Wfrag + (((size_t)j * 32 + k) * 64 + lane) * 8);
        } else {
            const float* ws = Wf + (size_t)j * 16384 + (size_t)k * 512 + hi * 256 + o31;
#pragma unroll
            for (int e = 0; e < 8; ++e) fw[e] = (bf16)ws[e * 32];
        }
        f32x16 h = __builtin_amdgcn_mfma_f32_32x32x16_bf16(fw, fx, ZV16, 0, 0, 0);
        float a = 0.f;
        const float* vk = vb + k * 32;
#pragma unroll
        for (int qq = 0; qq < 4; ++qq) {
            float4 v4 = *reinterpret_cast<const float4*>(vk + qq * 8);
            a += h[qq * 4 + 0] * v4.x + h[qq * 4 + 1] * v4.y
               + h[qq * 4 + 2] * v4.z + h[qq * 4 + 3] * v4.w;
        }
        a += __shfl_xor(a, 32, 64);
        lk[k] = a;
    }

    float mx = lk[0];
#pragma unroll
    for (int k = 1; k < 32; ++k) mx = fmaxf(mx, lk[k]);
    float sm = 0.f;
#pragma unroll
    for (int k = 0; k < 32; ++k) { lk[k] = __expf(lk[k] - mx); sm += lk[k]; }
    float inv = 1.0f / sm;

    if (hi == 0) {
#pragma unroll
        for (int k = 0; k < 32; ++k) cl[jj][b][k] = lk[k] * inv;
    }
    __syncthreads();

#pragma unroll
    for (int j2 = 0; j2 < 2; ++j2) {
#pragma unroll
        for (int i = 0; i < 8; ++i) {
            int idx = i * 256 + tid;
            int kk = idx >> 6, bb = idx & 63;
            cbuf[((size_t)(j0 + j2) * 32 + kk) * 64 + bb] = cl[j2][bb][kk];
        }
    }
}

extern "C" void kernel_launch(void* const* d_in, const int* in_sizes, int n_in,
                              void* d_out, int out_size, void* d_ws, size_t ws_size,
                              hipStream_t stream)
{
    const float* X  = (const float*)d_in[0];   // [64, 2048, 16] f32
    const float* Wg = (const float*)d_in[1];   // [2048, 32, 16, 32] f32
    float* out = (float*)d_out;                // [64, 32, 32] f32

    const size_t WFRAG_B = (size_t)JJ * 32 * 64 * 8 * 2;   // 67108864
    const size_t XFRAG_B = (size_t)JJ * 2 * 64 * 8 * 2;    // 4194304
    const size_t VS_B    = 65536ull * 4;                   // 262144
    const size_t VT_B    = 65536ull * 4;                   // 262144
    const size_t CB_B    = (size_t)BB * JJ * KC * 4;       // 16777216 (fallback only)
    const size_t FIX_B   = VS_B + VT_B + CB_B;

    int P = 256;
    int useFrag = 1;
    bf16 *Wfrag = nullptr, *Xfrag = nullptr, *partial = nullptr;
    float *vsum = nullptr, *vsumT = nullptr, *cbuf = nullptr;

    char* p = (char*)d_ws;
    if (ws_size >= WFRAG_B + XFRAG_B + FIX_B + (size_t)P * 65536 * 2) {
        Wfrag = (bf16*)p;            p += WFRAG_B;
        Xfrag = (bf16*)p;            p += XFRAG_B;
    } else {
        useFrag = 0;
        size_t avail = (ws_size > FIX_B) ? (ws_size - FIX_B) / (65536 * 2) : 8;
        P = (int)(avail & ~7ull);    // multiple of 8 for the XCD swizzle
        if (P < 8) P = 8;
        if (P > 128) P = 128;
    }
    vsum    = (float*)p;  p += VS_B;
    vsumT   = (float*)p;  p += VT_B;
    cbuf    = (float*)p;  p += CB_B;
    partial = (bf16*)p;

    const int Jc = (JJ + P - 1) / P;

    if (useFrag) {
        prep_x3<<<dim3(1024), dim3(256), 0, stream>>>(X, Xfrag);

        // iter 0: fused W-prep + init (uniform c = 1/32)
        caps_init8<<<dim3(8 * P), dim3(512), 0, stream>>>(Xfrag, Wg, Wfrag, partial, Jc);
        caps_red<<<dim3(64), dim3(256), 0, stream>>>(partial, vsum, vsumT, out, P, 0, 0);

        // iter 1 (fully fused)
        caps_fused<<<dim3(2 * P), dim3(1024), 0, stream>>>(Xfrag, Wfrag, vsumT, partial, Jc);
        caps_red<<<dim3(64), dim3(256), 0, stream>>>(partial, vsum, vsumT, out, P, 1, 0);

        // iter 2 (fully fused, writes output)
        caps_fused<<<dim3(2 * P), dim3(1024), 0, stream>>>(Xfrag, Wfrag, vsumT, partial, Jc);
        caps_red<<<dim3(64), dim3(256), 0, stream>>>(partial, vsum, vsumT, out, P, 2, 1);
    } else {
        caps_mm32<0,0><<<dim3(4 * P), dim3(1024), 0, stream>>>(Xfrag, Wfrag, X, Wg, cbuf, partial, Jc);
        caps_red<<<dim3(64), dim3(256), 0, stream>>>(partial, vsum, vsumT, out, P, 0, 0);

        caps_logits32<0><<<dim3(1024), dim3(256), 0, stream>>>(Xfrag, Wfrag, X, Wg, vsum, cbuf);
        caps_mm32<0,1><<<dim3(4 * P), dim3(1024), 0, stream>>>(Xfrag, Wfrag, X, Wg, cbuf, partial, Jc);
        caps_red<<<dim3(64), dim3(256), 0, stream>>>(partial, vsum, vsumT, out, P, 1, 0);

        caps_logits32<0><<<dim3(1024), dim3(256), 0, stream>>>(Xfrag, Wfrag, X, Wg, vsum, cbuf);
        caps_mm32<0,1><<<dim3(4 * P), dim3(1024), 0, stream>>>(Xfrag, Wfrag, X, Wg, cbuf, partial, Jc);
        caps_red<<<dim3(64), dim3(256), 0, stream>>>(partial, vsum, vsumT, out, P, 2, 1);
    }
}

// Round 15
// 162.789 us; speedup vs baseline: 3.1811x; 3.1811x over previous
//
#include <hip/hip_runtime.h>
#include <hip/hip_bf16.h>

#define BB  64
#define JJ  2048
#define DI  16
#define KC  32
#define DOO 32
#define NKO 1024   // KC*DOO

typedef __bf16 bf16;
typedef __attribute__((ext_vector_type(8)))  __bf16 bf16x8;
typedef __attribute__((ext_vector_type(4)))  __bf16 bf16x4;
typedef __attribute__((ext_vector_type(4)))  float  f32x4;
typedef __attribute__((ext_vector_type(16))) float  f32x16;

// ======== 32x32x16 MFMA scheme ========
// D = A(32x16) * B(16x32).  A = W-slice (rows = o), B = X (cols = b). K = i (16).
// A-frag: lane l holds row o = l&31, k i = (l>>5)*8 + e
// B-frag: lane l holds col b = l&31, k i = (l>>5)*8 + e
// C/D   : col b = lane&31, row o = (reg&3) + 8*(reg>>2) + 4*(lane>>5)   [m74/m101]

// ---------------- prep: X f32 [B][J][Di] -> B-fragment layout ----------------
__global__ __launch_bounds__(256)
void prep_x3(const float* __restrict__ X, bf16* __restrict__ Xfrag)
{
    int flat = blockIdx.x * 256 + threadIdx.x;    // < 262144
    int lane = flat & 63;
    int c01  = (flat >> 6) & 1;
    int j    = flat >> 7;
    int b    = c01 * 32 + (lane & 31);
    int i0   = (lane >> 5) * 8;
    const float* src = X + ((size_t)b * JJ + j) * DI + i0;
    bf16x8 o8;
#pragma unroll
    for (int e = 0; e < 8; ++e) o8[e] = (bf16)src[e];
    *reinterpret_cast<bf16x8*>(Xfrag + (size_t)flat * 8) = o8;
}

// XCD-aware decodes (bijective for the grids used).
__device__ __forceinline__ void decode_qjr(int id, int& q, int& jr)   // grid 4P, P%8==0
{
    q = (id >> 3) & 3; jr = ((id >> 5) << 3) | (id & 7);
}
__device__ __forceinline__ void decode_q8(int id, int& q8, int& jr)   // grid 8P, P%8==0
{
    q8 = (id >> 3) & 7; jr = ((id >> 6) << 3) | (id & 7);
}
__device__ __forceinline__ int decode_jg(int id)    // grid 1024
{
    return (id & 7) * 128 + (id >> 3);
}

// ---------------- fused prep+init, 2-j batched (balanced Wfrag store duty) ----------------
__global__ __launch_bounds__(512, 6)
void caps_init8(const bf16* __restrict__ Xfrag, const float* __restrict__ Wg,
                bf16* __restrict__ Wfrag, bf16* __restrict__ partial, int Jc)
{
    const int tid  = threadIdx.x;
    const int w    = tid >> 6;
    const int lane = tid & 63;
    const int o31  = lane & 31;
    const int hi   = lane >> 5;
    int q8, jr; decode_q8(blockIdx.x, q8, jr);
    const int unit = q8 * 8 + w;
    const int k    = unit & 31;
    const int c01  = unit >> 5;

    f32x16 acc = {};

    const int j0 = jr * Jc;
    int jend = j0 + Jc; if (jend > JJ) jend = JJ;

    int j = j0;
    for (; j + 1 < jend; j += 2) {
        const float* ws0 = Wg + (size_t)j * 16384 + (size_t)k * 512 + hi * 256 + o31;
        const float* ws1 = ws0 + 16384;
        float a0[8], a1[8];
#pragma unroll
        for (int e = 0; e < 8; ++e) a0[e] = ws0[e * 32];
#pragma unroll
        for (int e = 0; e < 8; ++e) a1[e] = ws1[e * 32];
        bf16x8 fw0, fw1;
#pragma unroll
        for (int e = 0; e < 8; ++e) { fw0[e] = (bf16)a0[e]; fw1[e] = (bf16)a1[e]; }
        // balanced store duty: c01=0 writes even j, c01=1 writes odd j (each exactly once)
        if (c01 == 0)
            *reinterpret_cast<bf16x8*>(Wfrag + (((size_t)j * 32 + k) * 64 + lane) * 8)       = fw0;
        else
            *reinterpret_cast<bf16x8*>(Wfrag + (((size_t)(j + 1) * 32 + k) * 64 + lane) * 8) = fw1;
        bf16x8 fx0 = *reinterpret_cast<const bf16x8*>(Xfrag + (((size_t)j * 2 + c01) * 64 + lane) * 8);
        bf16x8 fx1 = *reinterpret_cast<const bf16x8*>(Xfrag + (((size_t)(j + 1) * 2 + c01) * 64 + lane) * 8);
        acc = __builtin_amdgcn_mfma_f32_32x32x16_bf16(fw0, fx0, acc, 0, 0, 0);
        acc = __builtin_amdgcn_mfma_f32_32x32x16_bf16(fw1, fx1, acc, 0, 0, 0);
    }
    for (; j < jend; ++j) {
        const float* ws = Wg + (size_t)j * 16384 + (size_t)k * 512 + hi * 256 + o31;
        bf16x8 fw;
#pragma unroll
        for (int e = 0; e < 8; ++e) fw[e] = (bf16)ws[e * 32];
        if (c01 == 0)
            *reinterpret_cast<bf16x8*>(Wfrag + (((size_t)j * 32 + k) * 64 + lane) * 8) = fw;
        bf16x8 fx = *reinterpret_cast<const bf16x8*>(Xfrag + (((size_t)j * 2 + c01) * 64 + lane) * 8);
        acc = __builtin_amdgcn_mfma_f32_32x32x16_bf16(fw, fx, acc, 0, 0, 0);
    }

    bf16* pout = partial + (size_t)jr * (BB * NKO);
#pragma unroll
    for (int qq = 0; qq < 4; ++qq) {
        bf16x4 o4;
#pragma unroll
        for (int rr = 0; rr < 4; ++rr) o4[rr] = (bf16)(acc[qq * 4 + rr] * 0.03125f);
        *reinterpret_cast<bf16x4*>(pout + (((size_t)unit * 4 + qq) * 64 + lane) * 4) = o4;
    }
}

// ---------------- accum, 2-deep software pipeline ----------------
__global__ __launch_bounds__(512, 6)
void caps_accum2(const bf16* __restrict__ Xfrag, const bf16* __restrict__ Wfrag,
                 const float* __restrict__ cbuf, bf16* __restrict__ partial, int Jc)
{
    const int tid  = threadIdx.x;
    const int w    = tid >> 6;
    const int lane = tid & 63;
    const int o31  = lane & 31;
    int q8, jr; decode_q8(blockIdx.x, q8, jr);
    const int unit = q8 * 8 + w;
    const int k    = unit & 31;
    const int c01  = unit >> 5;
    const int b    = c01 * 32 + o31;

    const f32x16 ZV16 = {};
    f32x16 acc = ZV16;

    const int j0 = jr * Jc;
    int jend = j0 + Jc; if (jend > JJ) jend = JJ;

    auto ldx = [&](int j) {
        return *reinterpret_cast<const bf16x8*>(Xfrag + (((size_t)j * 2 + c01) * 64 + lane) * 8);
    };
    auto ldw = [&](int j) {
        return *reinterpret_cast<const bf16x8*>(Wfrag + (((size_t)j * 32 + k) * 64 + lane) * 8);
    };
    auto ldc = [&](int j) {
        return cbuf[((size_t)j * 32 + k) * 64 + b];
    };

    bf16x8 fx = ldx(j0), fw = ldw(j0);
    float  cw = ldc(j0);

    for (int j = j0; j < jend; ++j) {
        const int jn = (j + 1 < jend) ? j + 1 : j;
        bf16x8 nfx = ldx(jn);
        bf16x8 nfw = ldw(jn);
        float  ncw = ldc(jn);
        f32x16 h = __builtin_amdgcn_mfma_f32_32x32x16_bf16(fw, fx, ZV16, 0, 0, 0);
#pragma unroll
        for (int r = 0; r < 16; ++r) acc[r] += cw * h[r];
        fx = nfx; fw = nfw; cw = ncw;
    }

    bf16* pout = partial + (size_t)jr * (BB * NKO);
#pragma unroll
    for (int qq = 0; qq < 4; ++qq) {
        bf16x4 o4;
#pragma unroll
        for (int rr = 0; rr < 4; ++rr) o4[rr] = (bf16)(acc[qq * 4 + rr]);
        *reinterpret_cast<bf16x4*>(pout + (((size_t)unit * 4 + qq) * 64 + lane) * 4) = o4;
    }
}

// ---------------- logits: coalesced vsumT reads, 2-j batch, lane-local softmax ----------------
__global__ __launch_bounds__(512, 6)
void caps_logits8(const bf16* __restrict__ Xfrag, const bf16* __restrict__ Wfrag,
                  const float* __restrict__ vsumT, float* __restrict__ cbuf)
{
    __shared__ float lex[2][2][32][32];   // [c01][jj][k][b31] = 16 KB

    const int tid  = threadIdx.x;
    const int wv   = tid >> 6;
    const int lane = tid & 63;
    const int b31  = lane & 31;
    const int hi   = lane >> 5;
    const int c01  = wv & 1;
    const int kh2  = wv >> 1;            // 0..3
    const int jg   = decode_jg(blockIdx.x);
    const int j0   = jg * 2;
    const int b    = c01 * 32 + b31;

    const f32x16 ZV16 = {};

    bf16x8 fx0 = *reinterpret_cast<const bf16x8*>(Xfrag + (((size_t)j0 * 2 + c01) * 64 + lane) * 8);
    bf16x8 fx1 = *reinterpret_cast<const bf16x8*>(Xfrag + (((size_t)(j0 + 1) * 2 + c01) * 64 + lane) * 8);

    float lk[2][8];
#pragma unroll
    for (int kk = 0; kk < 8; ++kk) {
        const int k = kh2 * 8 + kk;
        const float* vt = vsumT + (size_t)k * 2048 + hi * 256 + b;
        float v[16];
#pragma unroll
        for (int qq = 0; qq < 4; ++qq)
#pragma unroll
            for (int rr = 0; rr < 4; ++rr)
                v[qq * 4 + rr] = vt[qq * 512 + rr * 64];
        const bf16* wf = Wfrag + (((size_t)j0 * 32 + k) * 64 + lane) * 8;
        bf16x8 fwa = *reinterpret_cast<const bf16x8*>(wf);
        bf16x8 fwb = *reinterpret_cast<const bf16x8*>(wf + 16384);
        f32x16 h0 = __builtin_amdgcn_mfma_f32_32x32x16_bf16(fwa, fx0, ZV16, 0, 0, 0);
        float a0 = 0.f;
#pragma unroll
        for (int r = 0; r < 16; ++r) a0 += h0[r] * v[r];
        f32x16 h1 = __builtin_amdgcn_mfma_f32_32x32x16_bf16(fwb, fx1, ZV16, 0, 0, 0);
        float a1 = 0.f;
#pragma unroll
        for (int r = 0; r < 16; ++r) a1 += h1[r] * v[r];
        a0 += __shfl_xor(a0, 32, 64);
        a1 += __shfl_xor(a1, 32, 64);
        lk[0][kk] = a0; lk[1][kk] = a1;
    }

    if (hi == 0) {
#pragma unroll
        for (int jj = 0; jj < 2; ++jj)
#pragma unroll
            for (int kk = 0; kk < 8; ++kk)
                lex[c01][jj][kh2 * 8 + kk][b31] = lk[jj][kk];
    }
    __syncthreads();

#pragma unroll
    for (int jj = 0; jj < 2; ++jj) {
        float mx = lex[c01][jj][0][b31];
#pragma unroll
        for (int k = 1; k < 32; ++k) mx = fmaxf(mx, lex[c01][jj][k][b31]);
        float sm = 0.f;
#pragma unroll
        for (int k = 0; k < 32; ++k) sm += __expf(lex[c01][jj][k][b31] - mx);
        float inv = 1.0f / sm;
#pragma unroll
        for (int kk = 0; kk < 8; ++kk)
            lk[jj][kk] = __expf(lk[jj][kk] - mx) * inv;
    }
    __syncthreads();

    if (hi == 0) {
#pragma unroll
        for (int jj = 0; jj < 2; ++jj)
#pragma unroll
            for (int kk = 0; kk < 8; ++kk)
                lex[c01][jj][kh2 * 8 + kk][b31] = lk[jj][kk];
    }
    __syncthreads();

    float* cj = cbuf + (size_t)j0 * 2048;
#pragma unroll
    for (int it = 0; it < 8; ++it) {
        int idx = it * 512 + tid;            // < 4096
        int b64 = idx & 63;
        int k   = (idx >> 6) & 31;
        int j2  = idx >> 11;
        cj[(size_t)j2 * 2048 + k * 64 + b64] = lex[b64 >> 5][j2][k][b64 & 31];
    }
}

// ---------------- merged reduce: sum P slices + squash + update vsum/vsumT/out ----------------
__global__ __launch_bounds__(256)
void caps_red(const bf16* __restrict__ partial, float* __restrict__ vsum, float* __restrict__ vsumT,
              float* __restrict__ out, int P, int vmode, int wout)
{
    __shared__ float lds[4][32];
    const int unit = blockIdx.x;          // 0..63
    const int tid  = threadIdx.x;
    const int b31  = tid & 31;
    const int hi   = (tid >> 5) & 1;
    const int qq   = tid >> 6;
    const int k    = unit & 31;
    const int c01  = unit >> 5;

    const bf16* base = partial + (size_t)unit * 1024 + (size_t)tid * 4;
    f32x4 a = {};
    int p = 0;
    for (; p + 8 <= P; p += 8) {
        bf16x4 v[8];
#pragma unroll
        for (int u = 0; u < 8; ++u)
            v[u] = *reinterpret_cast<const bf16x4*>(base + (size_t)(p + u) * 65536);
#pragma unroll
        for (int u = 0; u < 8; ++u)
#pragma unroll
            for (int rr = 0; rr < 4; ++rr) a[rr] += (float)v[u][rr];
    }
    for (; p < P; ++p) {
        bf16x4 v = *reinterpret_cast<const bf16x4*>(base + (size_t)p * 65536);
#pragma unroll
        for (int rr = 0; rr < 4; ++rr) a[rr] += (float)v[rr];
    }

    float s2l = a[0] * a[0] + a[1] * a[1] + a[2] * a[2] + a[3] * a[3];
    s2l += __shfl_xor(s2l, 32, 64);
    if ((tid & 63) < 32) lds[qq][b31] = s2l;
    __syncthreads();
    float s2 = lds[0][b31] + lds[1][b31] + lds[2][b31] + lds[3][b31];
    float scale = s2 / (1.0f + s2) / sqrtf(s2 + 1e-7f);

    const int b  = c01 * 32 + b31;
    const int o0 = qq * 8 + hi * 4;
    size_t e0 = ((size_t)b * KC + k) * DOO + o0;
    float4 wv, nv;
    wv.x = scale * a[0]; wv.y = scale * a[1]; wv.z = scale * a[2]; wv.w = scale * a[3];
    if (vmode == 0) {
        nv = wv;
    } else if (vmode == 1) {
        float4 ov = *reinterpret_cast<const float4*>(vsum + e0);
        nv.x = ov.x + wv.x; nv.y = ov.y + wv.y; nv.z = ov.z + wv.z; nv.w = ov.w + wv.w;
    }
    if (vmode < 2) {
        *reinterpret_cast<float4*>(vsum + e0) = nv;
        vsumT[((size_t)k * 32 + o0 + 0) * 64 + b] = nv.x;
        vsumT[((size_t)k * 32 + o0 + 1) * 64 + b] = nv.y;
        vsumT[((size_t)k * 32 + o0 + 2) * 64 + b] = nv.z;
        vsumT[((size_t)k * 32 + o0 + 3) * 64 + b] = nv.w;
    }
    if (wout) *reinterpret_cast<float4*>(out + e0) = wv;
}

// ---------------- fallback kernels (raw f32 path) ----------------
template<int UF, int MODE>
__global__ __launch_bounds__(1024, 8)
void caps_mm32(const bf16* __restrict__ Xfrag, const bf16* __restrict__ Wfrag,
               const float* __restrict__ Xf, const float* __restrict__ Wf,
               const float* __restrict__ cbuf, bf16* __restrict__ partial, int Jc)
{
    const int tid  = threadIdx.x;
    const int w    = tid >> 6;
    const int lane = tid & 63;
    const int o31  = lane & 31;
    const int hi   = lane >> 5;
    int q, jr; decode_qjr(blockIdx.x, q, jr);
    const int unit = q * 16 + w;
    const int k    = unit & 31;
    const int c01  = unit >> 5;
    const int b    = c01 * 32 + o31;

    const f32x16 ZV16 = {};
    f32x16 acc = ZV16;

    const int j0 = jr * Jc;
    int jend = j0 + Jc; if (jend > JJ) jend = JJ;

    for (int j = j0; j < jend; ++j) {
        bf16x8 fx, fw;
        if constexpr (UF) {
            fx = *reinterpret_cast<const bf16x8*>(Xfrag + (((size_t)j * 2 + c01) * 64 + lane) * 8);
            fw = *reinterpret_cast<const bf16x8*>(Wfrag + (((size_t)j * 32 + k) * 64 + lane) * 8);
        } else {
            const float* xs = Xf + ((size_t)b * JJ + j) * DI + hi * 8;
#pragma unroll
            for (int e = 0; e < 8; ++e) fx[e] = (bf16)xs[e];
            const float* ws = Wf + (size_t)j * 16384 + (size_t)k * 512 + hi * 256 + o31;
#pragma unroll
            for (int e = 0; e < 8; ++e) fw[e] = (bf16)ws[e * 32];
        }
        if constexpr (MODE == 0) {
            acc = __builtin_amdgcn_mfma_f32_32x32x16_bf16(fw, fx, acc, 0, 0, 0);
        } else {
            float cw = cbuf[((size_t)j * 32 + k) * 64 + b];
            f32x16 h = __builtin_amdgcn_mfma_f32_32x32x16_bf16(fw, fx, ZV16, 0, 0, 0);
#pragma unroll
            for (int r = 0; r < 16; ++r) acc[r] += cw * h[r];
        }
    }

    const float esc = (MODE == 0) ? 0.03125f : 1.0f;
    bf16* pout = partial + (size_t)jr * (BB * NKO);
#pragma unroll
    for (int qq = 0; qq < 4; ++qq) {
        bf16x4 o4;
#pragma unroll
        for (int rr = 0; rr < 4; ++rr) o4[rr] = (bf16)(acc[qq * 4 + rr] * esc);
        *reinterpret_cast<bf16x4*>(pout + (((size_t)unit * 4 + qq) * 64 + lane) * 4) = o4;
    }
}

template<int UF>
__global__ __launch_bounds__(256, 6)
void caps_logits32(const bf16* __restrict__ Xfrag, const bf16* __restrict__ Wfrag,
                   const float* __restrict__ Xf, const float* __restrict__ Wf,
                   const float* __restrict__ vsum, float* __restrict__ cbuf)
{
    __shared__ float cl[2][64][33];

    const int tid  = threadIdx.x;
    const int w    = tid >> 6;
    const int lane = tid & 63;
    const int o31  = lane & 31;
    const int hi   = lane >> 5;
    const int jg   = decode_jg(blockIdx.x);
    const int j0   = jg * 2;
    const int jj   = w >> 1;
    const int c01  = w & 1;
    const int j    = j0 + jj;
    const int b    = c01 * 32 + o31;

    const f32x16 ZV16 = {};

    bf16x8 fx;
    if constexpr (UF) {
        fx = *reinterpret_cast<const bf16x8*>(Xfrag + (((size_t)j * 2 + c01) * 64 + lane) * 8);
    } else {
        const float* xs = Xf + ((size_t)b * JJ + j) * DI + hi * 8;
#pragma unroll
        for (int e = 0; e < 8; ++e) fx[e] = (bf16)xs[e];
    }

    const float* vb = vsum + (size_t)b * NKO + hi * 4;
    float lk[32];
#pragma unroll
    for (int k = 0; k < 32; ++k) {
        bf16x8 fw;
        if constexpr (UF) {
            fw = *reinterpret_cast<const bf16x8*>(Wfrag + (((size_t)j * 32 + k) * 64 + lane) * 8);
        } else {
            const float* ws = Wf + (size_t)j * 16384 + (size_t)k * 512 + hi * 256 + o31;
#pragma unroll
            for (int e = 0; e < 8; ++e) fw[e] = (bf16)ws[e * 32];
        }
        f32x16 h = __builtin_amdgcn_mfma_f32_32x32x16_bf16(fw, fx, ZV16, 0, 0, 0);
        float a = 0.f;
        const float* vk = vb + k * 32;
#pragma unroll
        for (int qq = 0; qq < 4; ++qq) {
            float4 v4 = *reinterpret_cast<const float4*>(vk + qq * 8);
            a += h[qq * 4 + 0] * v4.x + h[qq * 4 + 1] * v4.y
               + h[qq * 4 + 2] * v4.z + h[qq * 4 + 3] * v4.w;
        }
        a += __shfl_xor(a, 32, 64);
        lk[k] = a;
    }

    float mx = lk[0];
#pragma unroll
    for (int k = 1; k < 32; ++k) mx = fmaxf(mx, lk[k]);
    float sm = 0.f;
#pragma unroll
    for (int k = 0; k < 32; ++k) { lk[k] = __expf(lk[k] - mx); sm += lk[k]; }
    float inv = 1.0f / sm;

    if (hi == 0) {
#pragma unroll
        for (int k = 0; k < 32; ++k) cl[jj][b][k] = lk[k] * inv;
    }
    __syncthreads();

#pragma unroll
    for (int j2 = 0; j2 < 2; ++j2) {
#pragma unroll
        for (int i = 0; i < 8; ++i) {
            int idx = i * 256 + tid;
            int kk = idx >> 6, bb = idx & 63;
            cbuf[((size_t)(j0 + j2) * 32 + kk) * 64 + bb] = cl[j2][bb][kk];
        }
    }
}

extern "C" void kernel_launch(void* const* d_in, const int* in_sizes, int n_in,
                              void* d_out, int out_size, void* d_ws, size_t ws_size,
                              hipStream_t stream)
{
    const float* X  = (const float*)d_in[0];   // [64, 2048, 16] f32
    const float* Wg = (const float*)d_in[1];   // [2048, 32, 16, 32] f32
    float* out = (float*)d_out;                // [64, 32, 32] f32

    const size_t WFRAG_B = (size_t)JJ * 32 * 64 * 8 * 2;   // 67108864
    const size_t XFRAG_B = (size_t)JJ * 2 * 64 * 8 * 2;    // 4194304
    const size_t VS_B    = 65536ull * 4;                   // 262144
    const size_t VT_B    = 65536ull * 4;                   // 262144 (transposed copy)
    const size_t CB_B    = (size_t)BB * JJ * KC * 4;       // 16777216
    const size_t FIX_B   = VS_B + VT_B + CB_B;

    int P = 128;
    int useFrag = 1;
    bf16 *Wfrag = nullptr, *Xfrag = nullptr, *partial = nullptr;
    float *vsum = nullptr, *vsumT = nullptr, *cbuf = nullptr;

    char* p = (char*)d_ws;
    if (ws_size >= WFRAG_B + XFRAG_B + FIX_B + (size_t)P * 65536 * 2) {
        Wfrag = (bf16*)p;            p += WFRAG_B;
        Xfrag = (bf16*)p;            p += XFRAG_B;
    } else {
        useFrag = 0;
        size_t avail = (ws_size > FIX_B) ? (ws_size - FIX_B) / (65536 * 2) : 8;
        P = (int)(avail & ~7ull);    // multiple of 8 for the XCD swizzle
        if (P < 8) P = 8;
        if (P > 128) P = 128;
    }
    vsum    = (float*)p;  p += VS_B;
    vsumT   = (float*)p;  p += VT_B;
    cbuf    = (float*)p;  p += CB_B;
    partial = (bf16*)p;

    const int Jc = (JJ + P - 1) / P;

    if (useFrag) {
        prep_x3<<<dim3(1024), dim3(256), 0, stream>>>(X, Xfrag);

        // iter 0: fused W-prep + init (uniform c = 1/32)
        caps_init8<<<dim3(8 * P), dim3(512), 0, stream>>>(Xfrag, Wg, Wfrag, partial, Jc);
        caps_red<<<dim3(64), dim3(256), 0, stream>>>(partial, vsum, vsumT, out, P, 0, 0);

        // iter 1
        caps_logits8<<<dim3(1024), dim3(512), 0, stream>>>(Xfrag, Wfrag, vsumT, cbuf);
        caps_accum2<<<dim3(8 * P), dim3(512), 0, stream>>>(Xfrag, Wfrag, cbuf, partial, Jc);
        caps_red<<<dim3(64), dim3(256), 0, stream>>>(partial, vsum, vsumT, out, P, 1, 0);

        // iter 2 (writes output)
        caps_logits8<<<dim3(1024), dim3(512), 0, stream>>>(Xfrag, Wfrag, vsumT, cbuf);
        caps_accum2<<<dim3(8 * P), dim3(512), 0, stream>>>(Xfrag, Wfrag, cbuf, partial, Jc);
        caps_red<<<dim3(64), dim3(256), 0, stream>>>(partial, vsum, vsumT, out, P, 2, 1);
    } else {
        caps_mm32<0,0><<<dim3(4 * P), dim3(1024), 0, stream>>>(Xfrag, Wfrag, X, Wg, cbuf, partial, Jc);
        caps_red<<<dim3(64), dim3(256), 0, stream>>>(partial, vsum, vsumT, out, P, 0, 0);

        caps_logits32<0><<<dim3(1024), dim3(256), 0, stream>>>(Xfrag, Wfrag, X, Wg, vsum, cbuf);
        caps_mm32<0,1><<<dim3(4 * P), dim3(1024), 0, stream>>>(Xfrag, Wfrag, X, Wg, cbuf, partial, Jc);
        caps_red<<<dim3(64), dim3(256), 0, stream>>>(partial, vsum, vsumT, out, P, 1, 0);

        caps_logits32<0><<<dim3(1024), dim3(256), 0, stream>>>(Xfrag, Wfrag, X, Wg, vsum, cbuf);
        caps_mm32<0,1><<<dim3(4 * P), dim3(1024), 0, stream>>>(Xfrag, Wfrag, X, Wg, cbuf, partial, Jc);
        caps_red<<<dim3(64), dim3(256), 0, stream>>>(partial, vsum, vsumT, out, P, 2, 1);
    }
}

// Round 16
// 160.483 us; speedup vs baseline: 3.2268x; 1.0144x over previous
//
#include <hip/hip_runtime.h>
#include <hip/hip_bf16.h>

#define BB  64
#define JJ  2048
#define DI  16
#define KC  32
#define DOO 32
#define NKO 1024   // KC*DOO

typedef __bf16 bf16;
typedef __attribute__((ext_vector_type(8)))  __bf16 bf16x8;
typedef __attribute__((ext_vector_type(4)))  __bf16 bf16x4;
typedef __attribute__((ext_vector_type(4)))  float  f32x4;
typedef __attribute__((ext_vector_type(16))) float  f32x16;

// ======== 32x32x16 MFMA scheme ========
// D = A(32x16) * B(16x32).  A = W-slice (rows = o), B = X (cols = b). K = i (16).
// A-frag: lane l holds row o = l&31, k i = (l>>5)*8 + e
// B-frag: lane l holds col b = l&31, k i = (l>>5)*8 + e
// C/D   : col b = lane&31, row o = (reg&3) + 8*(reg>>2) + 4*(lane>>5)   [m74/m101]

// ---------------- prep: X f32 [B][J][Di] -> B-fragment layout ----------------
__global__ __launch_bounds__(256)
void prep_x3(const float* __restrict__ X, bf16* __restrict__ Xfrag)
{
    int flat = blockIdx.x * 256 + threadIdx.x;    // < 262144
    int lane = flat & 63;
    int c01  = (flat >> 6) & 1;
    int j    = flat >> 7;
    int b    = c01 * 32 + (lane & 31);
    int i0   = (lane >> 5) * 8;
    const float* src = X + ((size_t)b * JJ + j) * DI + i0;
    bf16x8 o8;
#pragma unroll
    for (int e = 0; e < 8; ++e) o8[e] = (bf16)src[e];
    *reinterpret_cast<bf16x8*>(Xfrag + (size_t)flat * 8) = o8;
}

// XCD-aware decodes (bijective for the grids used).
__device__ __forceinline__ void decode_qjr(int id, int& q, int& jr)   // grid 4P, P%8==0
{
    q = (id >> 3) & 3; jr = ((id >> 5) << 3) | (id & 7);
}
__device__ __forceinline__ void decode_q8(int id, int& q8, int& jr)   // grid 8P, P%8==0
{
    q8 = (id >> 3) & 7; jr = ((id >> 6) << 3) | (id & 7);
}
__device__ __forceinline__ int decode_jg(int id)    // grid 1024
{
    return (id & 7) * 128 + (id >> 3);
}

// ---------------- fused prep+init, 4-j batched: one latency exposure per 4 j's ----------------
// Block 512 = 8 waves, grid 8P. unit = q8*8 + w = c01*32 + k.
// Store duty: c01=0 writes j+0,j+1; c01=1 writes j+2,j+3 (each (j,k,lane) exactly once).
__global__ __launch_bounds__(512, 6)
void caps_init9(const bf16* __restrict__ Xfrag, const float* __restrict__ Wg,
                bf16* __restrict__ Wfrag, bf16* __restrict__ partial, int Jc)
{
    const int tid  = threadIdx.x;
    const int w    = tid >> 6;
    const int lane = tid & 63;
    const int o31  = lane & 31;
    const int hi   = lane >> 5;
    int q8, jr; decode_q8(blockIdx.x, q8, jr);
    const int unit = q8 * 8 + w;
    const int k    = unit & 31;
    const int c01  = unit >> 5;

    f32x16 acc = {};

    const int j0 = jr * Jc;
    int jend = j0 + Jc; if (jend > JJ) jend = JJ;

    int j = j0;
    for (; j + 3 < jend; j += 4) {
        const float* wsb = Wg + (size_t)j * 16384 + (size_t)k * 512 + hi * 256 + o31;
        float a0[8], a1[8], a2[8], a3[8];
#pragma unroll
        for (int e = 0; e < 8; ++e) a0[e] = wsb[e * 32];
#pragma unroll
        for (int e = 0; e < 8; ++e) a1[e] = wsb[16384 + e * 32];
#pragma unroll
        for (int e = 0; e < 8; ++e) a2[e] = wsb[32768 + e * 32];
#pragma unroll
        for (int e = 0; e < 8; ++e) a3[e] = wsb[49152 + e * 32];
        bf16x8 fw0, fw1, fw2, fw3;
#pragma unroll
        for (int e = 0; e < 8; ++e) {
            fw0[e] = (bf16)a0[e]; fw1[e] = (bf16)a1[e];
            fw2[e] = (bf16)a2[e]; fw3[e] = (bf16)a3[e];
        }
        bf16* wfb = Wfrag + (((size_t)j * 32 + k) * 64 + lane) * 8;
        if (c01 == 0) {
            *reinterpret_cast<bf16x8*>(wfb)         = fw0;
            *reinterpret_cast<bf16x8*>(wfb + 16384) = fw1;
        } else {
            *reinterpret_cast<bf16x8*>(wfb + 32768) = fw2;
            *reinterpret_cast<bf16x8*>(wfb + 49152) = fw3;
        }
        const bf16* xfb = Xfrag + (((size_t)j * 2 + c01) * 64 + lane) * 8;
        bf16x8 fx0 = *reinterpret_cast<const bf16x8*>(xfb);
        bf16x8 fx1 = *reinterpret_cast<const bf16x8*>(xfb + 1024);
        bf16x8 fx2 = *reinterpret_cast<const bf16x8*>(xfb + 2048);
        bf16x8 fx3 = *reinterpret_cast<const bf16x8*>(xfb + 3072);
        acc = __builtin_amdgcn_mfma_f32_32x32x16_bf16(fw0, fx0, acc, 0, 0, 0);
        acc = __builtin_amdgcn_mfma_f32_32x32x16_bf16(fw1, fx1, acc, 0, 0, 0);
        acc = __builtin_amdgcn_mfma_f32_32x32x16_bf16(fw2, fx2, acc, 0, 0, 0);
        acc = __builtin_amdgcn_mfma_f32_32x32x16_bf16(fw3, fx3, acc, 0, 0, 0);
    }
    for (; j < jend; ++j) {   // tail (Jc not multiple of 4)
        const float* ws = Wg + (size_t)j * 16384 + (size_t)k * 512 + hi * 256 + o31;
        bf16x8 fw;
#pragma unroll
        for (int e = 0; e < 8; ++e) fw[e] = (bf16)ws[e * 32];
        if (c01 == 0)
            *reinterpret_cast<bf16x8*>(Wfrag + (((size_t)j * 32 + k) * 64 + lane) * 8) = fw;
        bf16x8 fx = *reinterpret_cast<const bf16x8*>(Xfrag + (((size_t)j * 2 + c01) * 64 + lane) * 8);
        acc = __builtin_amdgcn_mfma_f32_32x32x16_bf16(fw, fx, acc, 0, 0, 0);
    }

    bf16* pout = partial + (size_t)jr * (BB * NKO);
#pragma unroll
    for (int qq = 0; qq < 4; ++qq) {
        bf16x4 o4;
#pragma unroll
        for (int rr = 0; rr < 4; ++rr) o4[rr] = (bf16)(acc[qq * 4 + rr] * 0.03125f);
        *reinterpret_cast<bf16x4*>(pout + (((size_t)unit * 4 + qq) * 64 + lane) * 4) = o4;
    }
}

// ---------------- accum, 2-deep software pipeline ----------------
__global__ __launch_bounds__(512, 6)
void caps_accum2(const bf16* __restrict__ Xfrag, const bf16* __restrict__ Wfrag,
                 const float* __restrict__ cbuf, bf16* __restrict__ partial, int Jc)
{
    const int tid  = threadIdx.x;
    const int w    = tid >> 6;
    const int lane = tid & 63;
    const int o31  = lane & 31;
    int q8, jr; decode_q8(blockIdx.x, q8, jr);
    const int unit = q8 * 8 + w;
    const int k    = unit & 31;
    const int c01  = unit >> 5;
    const int b    = c01 * 32 + o31;

    const f32x16 ZV16 = {};
    f32x16 acc = ZV16;

    const int j0 = jr * Jc;
    int jend = j0 + Jc; if (jend > JJ) jend = JJ;

    auto ldx = [&](int j) {
        return *reinterpret_cast<const bf16x8*>(Xfrag + (((size_t)j * 2 + c01) * 64 + lane) * 8);
    };
    auto ldw = [&](int j) {
        return *reinterpret_cast<const bf16x8*>(Wfrag + (((size_t)j * 32 + k) * 64 + lane) * 8);
    };
    auto ldc = [&](int j) {
        return cbuf[((size_t)j * 32 + k) * 64 + b];
    };

    bf16x8 fx = ldx(j0), fw = ldw(j0);
    float  cw = ldc(j0);

    for (int j = j0; j < jend; ++j) {
        const int jn = (j + 1 < jend) ? j + 1 : j;
        bf16x8 nfx = ldx(jn);
        bf16x8 nfw = ldw(jn);
        float  ncw = ldc(jn);
        f32x16 h = __builtin_amdgcn_mfma_f32_32x32x16_bf16(fw, fx, ZV16, 0, 0, 0);
#pragma unroll
        for (int r = 0; r < 16; ++r) acc[r] += cw * h[r];
        fx = nfx; fw = nfw; cw = ncw;
    }

    bf16* pout = partial + (size_t)jr * (BB * NKO);
#pragma unroll
    for (int qq = 0; qq < 4; ++qq) {
        bf16x4 o4;
#pragma unroll
        for (int rr = 0; rr < 4; ++rr) o4[rr] = (bf16)(acc[qq * 4 + rr]);
        *reinterpret_cast<bf16x4*>(pout + (((size_t)unit * 4 + qq) * 64 + lane) * 4) = o4;
    }
}

// ---------------- logits: coalesced vsumT reads, 2-j batch, lane-local softmax ----------------
__global__ __launch_bounds__(512, 6)
void caps_logits8(const bf16* __restrict__ Xfrag, const bf16* __restrict__ Wfrag,
                  const float* __restrict__ vsumT, float* __restrict__ cbuf)
{
    __shared__ float lex[2][2][32][32];   // [c01][jj][k][b31] = 16 KB

    const int tid  = threadIdx.x;
    const int wv   = tid >> 6;
    const int lane = tid & 63;
    const int b31  = lane & 31;
    const int hi   = lane >> 5;
    const int c01  = wv & 1;
    const int kh2  = wv >> 1;            // 0..3
    const int jg   = decode_jg(blockIdx.x);
    const int j0   = jg * 2;
    const int b    = c01 * 32 + b31;

    const f32x16 ZV16 = {};

    bf16x8 fx0 = *reinterpret_cast<const bf16x8*>(Xfrag + (((size_t)j0 * 2 + c01) * 64 + lane) * 8);
    bf16x8 fx1 = *reinterpret_cast<const bf16x8*>(Xfrag + (((size_t)(j0 + 1) * 2 + c01) * 64 + lane) * 8);

    float lk[2][8];
#pragma unroll
    for (int kk = 0; kk < 8; ++kk) {
        const int k = kh2 * 8 + kk;
        const float* vt = vsumT + (size_t)k * 2048 + hi * 256 + b;
        float v[16];
#pragma unroll
        for (int qq = 0; qq < 4; ++qq)
#pragma unroll
            for (int rr = 0; rr < 4; ++rr)
                v[qq * 4 + rr] = vt[qq * 512 + rr * 64];
        const bf16* wf = Wfrag + (((size_t)j0 * 32 + k) * 64 + lane) * 8;
        bf16x8 fwa = *reinterpret_cast<const bf16x8*>(wf);
        bf16x8 fwb = *reinterpret_cast<const bf16x8*>(wf + 16384);
        f32x16 h0 = __builtin_amdgcn_mfma_f32_32x32x16_bf16(fwa, fx0, ZV16, 0, 0, 0);
        float a0 = 0.f;
#pragma unroll
        for (int r = 0; r < 16; ++r) a0 += h0[r] * v[r];
        f32x16 h1 = __builtin_amdgcn_mfma_f32_32x32x16_bf16(fwb, fx1, ZV16, 0, 0, 0);
        float a1 = 0.f;
#pragma unroll
        for (int r = 0; r < 16; ++r) a1 += h1[r] * v[r];
        a0 += __shfl_xor(a0, 32, 64);
        a1 += __shfl_xor(a1, 32, 64);
        lk[0][kk] = a0; lk[1][kk] = a1;
    }

    if (hi == 0) {
#pragma unroll
        for (int jj = 0; jj < 2; ++jj)
#pragma unroll
            for (int kk = 0; kk < 8; ++kk)
                lex[c01][jj][kh2 * 8 + kk][b31] = lk[jj][kk];
    }
    __syncthreads();

#pragma unroll
    for (int jj = 0; jj < 2; ++jj) {
        float mx = lex[c01][jj][0][b31];
#pragma unroll
        for (int k = 1; k < 32; ++k) mx = fmaxf(mx, lex[c01][jj][k][b31]);
        float sm = 0.f;
#pragma unroll
        for (int k = 0; k < 32; ++k) sm += __expf(lex[c01][jj][k][b31] - mx);
        float inv = 1.0f / sm;
#pragma unroll
        for (int kk = 0; kk < 8; ++kk)
            lk[jj][kk] = __expf(lk[jj][kk] - mx) * inv;
    }
    __syncthreads();

    if (hi == 0) {
#pragma unroll
        for (int jj = 0; jj < 2; ++jj)
#pragma unroll
            for (int kk = 0; kk < 8; ++kk)
                lex[c01][jj][kh2 * 8 + kk][b31] = lk[jj][kk];
    }
    __syncthreads();

    float* cj = cbuf + (size_t)j0 * 2048;
#pragma unroll
    for (int it = 0; it < 8; ++it) {
        int idx = it * 512 + tid;            // < 4096
        int b64 = idx & 63;
        int k   = (idx >> 6) & 31;
        int j2  = idx >> 11;
        cj[(size_t)j2 * 2048 + k * 64 + b64] = lex[b64 >> 5][j2][k][b64 & 31];
    }
}

// ---------------- merged reduce: sum P slices + squash + update vsum/vsumT/out ----------------
__global__ __launch_bounds__(256)
void caps_red(const bf16* __restrict__ partial, float* __restrict__ vsum, float* __restrict__ vsumT,
              float* __restrict__ out, int P, int vmode, int wout)
{
    __shared__ float lds[4][32];
    const int unit = blockIdx.x;          // 0..63
    const int tid  = threadIdx.x;
    const int b31  = tid & 31;
    const int hi   = (tid >> 5) & 1;
    const int qq   = tid >> 6;
    const int k    = unit & 31;
    const int c01  = unit >> 5;

    const bf16* base = partial + (size_t)unit * 1024 + (size_t)tid * 4;
    f32x4 a = {};
    int p = 0;
    for (; p + 8 <= P; p += 8) {
        bf16x4 v[8];
#pragma unroll
        for (int u = 0; u < 8; ++u)
            v[u] = *reinterpret_cast<const bf16x4*>(base + (size_t)(p + u) * 65536);
#pragma unroll
        for (int u = 0; u < 8; ++u)
#pragma unroll
            for (int rr = 0; rr < 4; ++rr) a[rr] += (float)v[u][rr];
    }
    for (; p < P; ++p) {
        bf16x4 v = *reinterpret_cast<const bf16x4*>(base + (size_t)p * 65536);
#pragma unroll
        for (int rr = 0; rr < 4; ++rr) a[rr] += (float)v[rr];
    }

    float s2l = a[0] * a[0] + a[1] * a[1] + a[2] * a[2] + a[3] * a[3];
    s2l += __shfl_xor(s2l, 32, 64);
    if ((tid & 63) < 32) lds[qq][b31] = s2l;
    __syncthreads();
    float s2 = lds[0][b31] + lds[1][b31] + lds[2][b31] + lds[3][b31];
    float scale = s2 / (1.0f + s2) / sqrtf(s2 + 1e-7f);

    const int b  = c01 * 32 + b31;
    const int o0 = qq * 8 + hi * 4;
    size_t e0 = ((size_t)b * KC + k) * DOO + o0;
    float4 wv, nv;
    wv.x = scale * a[0]; wv.y = scale * a[1]; wv.z = scale * a[2]; wv.w = scale * a[3];
    if (vmode == 0) {
        nv = wv;
    } else if (vmode == 1) {
        float4 ov = *reinterpret_cast<const float4*>(vsum + e0);
        nv.x = ov.x + wv.x; nv.y = ov.y + wv.y; nv.z = ov.z + wv.z; nv.w = ov.w + wv.w;
    }
    if (vmode < 2) {
        *reinterpret_cast<float4*>(vsum + e0) = nv;
        vsumT[((size_t)k * 32 + o0 + 0) * 64 + b] = nv.x;
        vsumT[((size_t)k * 32 + o0 + 1) * 64 + b] = nv.y;
        vsumT[((size_t)k * 32 + o0 + 2) * 64 + b] = nv.z;
        vsumT[((size_t)k * 32 + o0 + 3) * 64 + b] = nv.w;
    }
    if (wout) *reinterpret_cast<float4*>(out + e0) = wv;
}

// ---------------- fallback kernels (raw f32 path) ----------------
template<int UF, int MODE>
__global__ __launch_bounds__(1024, 8)
void caps_mm32(const bf16* __restrict__ Xfrag, const bf16* __restrict__ Wfrag,
               const float* __restrict__ Xf, const float* __restrict__ Wf,
               const float* __restrict__ cbuf, bf16* __restrict__ partial, int Jc)
{
    const int tid  = threadIdx.x;
    const int w    = tid >> 6;
    const int lane = tid & 63;
    const int o31  = lane & 31;
    const int hi   = lane >> 5;
    int q, jr; decode_qjr(blockIdx.x, q, jr);
    const int unit = q * 16 + w;
    const int k    = unit & 31;
    const int c01  = unit >> 5;
    const int b    = c01 * 32 + o31;

    const f32x16 ZV16 = {};
    f32x16 acc = ZV16;

    const int j0 = jr * Jc;
    int jend = j0 + Jc; if (jend > JJ) jend = JJ;

    for (int j = j0; j < jend; ++j) {
        bf16x8 fx, fw;
        if constexpr (UF) {
            fx = *reinterpret_cast<const bf16x8*>(Xfrag + (((size_t)j * 2 + c01) * 64 + lane) * 8);
            fw = *reinterpret_cast<const bf16x8*>(Wfrag + (((size_t)j * 32 + k) * 64 + lane) * 8);
        } else {
            const float* xs = Xf + ((size_t)b * JJ + j) * DI + hi * 8;
#pragma unroll
            for (int e = 0; e < 8; ++e) fx[e] = (bf16)xs[e];
            const float* ws = Wf + (size_t)j * 16384 + (size_t)k * 512 + hi * 256 + o31;
#pragma unroll
            for (int e = 0; e < 8; ++e) fw[e] = (bf16)ws[e * 32];
        }
        if constexpr (MODE == 0) {
            acc = __builtin_amdgcn_mfma_f32_32x32x16_bf16(fw, fx, acc, 0, 0, 0);
        } else {
            float cw = cbuf[((size_t)j * 32 + k) * 64 + b];
            f32x16 h = __builtin_amdgcn_mfma_f32_32x32x16_bf16(fw, fx, ZV16, 0, 0, 0);
#pragma unroll
            for (int r = 0; r < 16; ++r) acc[r] += cw * h[r];
        }
    }

    const float esc = (MODE == 0) ? 0.03125f : 1.0f;
    bf16* pout = partial + (size_t)jr * (BB * NKO);
#pragma unroll
    for (int qq = 0; qq < 4; ++qq) {
        bf16x4 o4;
#pragma unroll
        for (int rr = 0; rr < 4; ++rr) o4[rr] = (bf16)(acc[qq * 4 + rr] * esc);
        *reinterpret_cast<bf16x4*>(pout + (((size_t)unit * 4 + qq) * 64 + lane) * 4) = o4;
    }
}

template<int UF>
__global__ __launch_bounds__(256, 6)
void caps_logits32(const bf16* __restrict__ Xfrag, const bf16* __restrict__ Wfrag,
                   const float* __restrict__ Xf, const float* __restrict__ Wf,
                   const float* __restrict__ vsum, float* __restrict__ cbuf)
{
    __shared__ float cl[2][64][33];

    const int tid  = threadIdx.x;
    const int w    = tid >> 6;
    const int lane = tid & 63;
    const int o31  = lane & 31;
    const int hi   = lane >> 5;
    const int jg   = decode_jg(blockIdx.x);
    const int j0   = jg * 2;
    const int jj   = w >> 1;
    const int c01  = w & 1;
    const int j    = j0 + jj;
    const int b    = c01 * 32 + o31;

    const f32x16 ZV16 = {};

    bf16x8 fx;
    if constexpr (UF) {
        fx = *reinterpret_cast<const bf16x8*>(Xfrag + (((size_t)j * 2 + c01) * 64 + lane) * 8);
    } else {
        const float* xs = Xf + ((size_t)b * JJ + j) * DI + hi * 8;
#pragma unroll
        for (int e = 0; e < 8; ++e) fx[e] = (bf16)xs[e];
    }

    const float* vb = vsum + (size_t)b * NKO + hi * 4;
    float lk[32];
#pragma unroll
    for (int k = 0; k < 32; ++k) {
        bf16x8 fw;
        if constexpr (UF) {
            fw = *reinterpret_cast<const bf16x8*>(Wfrag + (((size_t)j * 32 + k) * 64 + lane) * 8);
        } else {
            const float* ws = Wf + (size_t)j * 16384 + (size_t)k * 512 + hi * 256 + o31;
#pragma unroll
            for (int e = 0; e < 8; ++e) fw[e] = (bf16)ws[e * 32];
        }
        f32x16 h = __builtin_amdgcn_mfma_f32_32x32x16_bf16(fw, fx, ZV16, 0, 0, 0);
        float a = 0.f;
        const float* vk = vb + k * 32;
#pragma unroll
        for (int qq = 0; qq < 4; ++qq) {
            float4 v4 = *reinterpret_cast<const float4*>(vk + qq * 8);
            a += h[qq * 4 + 0] * v4.x + h[qq * 4 + 1] * v4.y
               + h[qq * 4 + 2] * v4.z + h[qq * 4 + 3] * v4.w;
        }
        a += __shfl_xor(a, 32, 64);
        lk[k] = a;
    }

    float mx = lk[0];
#pragma unroll
    for (int k = 1; k < 32; ++k) mx = fmaxf(mx, lk[k]);
    float sm = 0.f;
#pragma unroll
    for (int k = 0; k < 32; ++k) { lk[k] = __expf(lk[k] - mx); sm += lk[k]; }
    float inv = 1.0f / sm;

    if (hi == 0) {
#pragma unroll
        for (int k = 0; k < 32; ++k) cl[jj][b][k] = lk[k] * inv;
    }
    __syncthreads();

#pragma unroll
    for (int j2 = 0; j2 < 2; ++j2) {
#pragma unroll
        for (int i = 0; i < 8; ++i) {
            int idx = i * 256 + tid;
            int kk = idx >> 6, bb = idx & 63;
            cbuf[((size_t)(j0 + j2) * 32 + kk) * 64 + bb] = cl[j2][bb][kk];
        }
    }
}

extern "C" void kernel_launch(void* const* d_in, const int* in_sizes, int n_in,
                              void* d_out, int out_size, void* d_ws, size_t ws_size,
                              hipStream_t stream)
{
    const float* X  = (const float*)d_in[0];   // [64, 2048, 16] f32
    const float* Wg = (const float*)d_in[1];   // [2048, 32, 16, 32] f32
    float* out = (float*)d_out;                // [64, 32, 32] f32

    const size_t WFRAG_B = (size_t)JJ * 32 * 64 * 8 * 2;   // 67108864
    const size_t XFRAG_B = (size_t)JJ * 2 * 64 * 8 * 2;    // 4194304
    const size_t VS_B    = 65536ull * 4;                   // 262144
    const size_t VT_B    = 65536ull * 4;                   // 262144 (transposed copy)
    const size_t CB_B    = (size_t)BB * JJ * KC * 4;       // 16777216
    const size_t FIX_B   = VS_B + VT_B + CB_B;

    int P = 128;
    int useFrag = 1;
    bf16 *Wfrag = nullptr, *Xfrag = nullptr, *partial = nullptr;
    float *vsum = nullptr, *vsumT = nullptr, *cbuf = nullptr;

    char* p = (char*)d_ws;
    if (ws_size >= WFRAG_B + XFRAG_B + FIX_B + (size_t)P * 65536 * 2) {
        Wfrag = (bf16*)p;            p += WFRAG_B;
        Xfrag = (bf16*)p;            p += XFRAG_B;
    } else {
        useFrag = 0;
        size_t avail = (ws_size > FIX_B) ? (ws_size - FIX_B) / (65536 * 2) : 8;
        P = (int)(avail & ~7ull);    // multiple of 8 for the XCD swizzle
        if (P < 8) P = 8;
        if (P > 128) P = 128;
    }
    vsum    = (float*)p;  p += VS_B;
    vsumT   = (float*)p;  p += VT_B;
    cbuf    = (float*)p;  p += CB_B;
    partial = (bf16*)p;

    const int Jc = (JJ + P - 1) / P;

    if (useFrag) {
        prep_x3<<<dim3(1024), dim3(256), 0, stream>>>(X, Xfrag);

        // iter 0: fused W-prep + init (uniform c = 1/32), 4-j batched
        caps_init9<<<dim3(8 * P), dim3(512), 0, stream>>>(Xfrag, Wg, Wfrag, partial, Jc);
        caps_red<<<dim3(64), dim3(256), 0, stream>>>(partial, vsum, vsumT, out, P, 0, 0);

        // iter 1
        caps_logits8<<<dim3(1024), dim3(512), 0, stream>>>(Xfrag, Wfrag, vsumT, cbuf);
        caps_accum2<<<dim3(8 * P), dim3(512), 0, stream>>>(Xfrag, Wfrag, cbuf, partial, Jc);
        caps_red<<<dim3(64), dim3(256), 0, stream>>>(partial, vsum, vsumT, out, P, 1, 0);

        // iter 2 (writes output)
        caps_logits8<<<dim3(1024), dim3(512), 0, stream>>>(Xfrag, Wfrag, vsumT, cbuf);
        caps_accum2<<<dim3(8 * P), dim3(512), 0, stream>>>(Xfrag, Wfrag, cbuf, partial, Jc);
        caps_red<<<dim3(64), dim3(256), 0, stream>>>(partial, vsum, vsumT, out, P, 2, 1);
    } else {
        caps_mm32<0,0><<<dim3(4 * P), dim3(1024), 0, stream>>>(Xfrag, Wfrag, X, Wg, cbuf, partial, Jc);
        caps_red<<<dim3(64), dim3(256), 0, stream>>>(partial, vsum, vsumT, out, P, 0, 0);

        caps_logits32<0><<<dim3(1024), dim3(256), 0, stream>>>(Xfrag, Wfrag, X, Wg, vsum, cbuf);
        caps_mm32<0,1><<<dim3(4 * P), dim3(1024), 0, stream>>>(Xfrag, Wfrag, X, Wg, cbuf, partial, Jc);
        caps_red<<<dim3(64), dim3(256), 0, stream>>>(partial, vsum, vsumT, out, P, 1, 0);

        caps_logits32<0><<<dim3(1024), dim3(256), 0, stream>>>(Xfrag, Wfrag, X, Wg, vsum, cbuf);
        caps_mm32<0,1><<<dim3(4 * P), dim3(1024), 0, stream>>>(Xfrag, Wfrag, X, Wg, cbuf, partial, Jc);
        caps_red<<<dim3(64), dim3(256), 0, stream>>>(partial, vsum, vsumT, out, P, 2, 1);
    }
}